// Round 21
// baseline (54.439 us; speedup 1.0000x reference)
//
#include <hip/hip_runtime.h>

// RoIAlign (torchvision semantics, aligned=false, sampling_ratio=2)
// features: [N=2, C=256, H=200, W=200] f32, rois: [K,5], out: [K,256,7,7] f32
constexpr int C = 256, H = 200, W = 200, NB = 2;
constexpr int PH = 7, PW = 7;
constexpr int NS = 14;             // fallback only
constexpr float SCALE = 0.125f;
// transposed tensor: T[cg:8][nb:2][y][x][32ch] f16 — 64B per (pixel,cgroup) = 1 line
constexpr int CG = 32, NCG = C / CG;
// fallback (R4) tiling
constexpr int CGF = 8, NGROUPF = C / CGF;

typedef float    f32x4 __attribute__((ext_vector_type(4)));
typedef _Float16 h2    __attribute__((ext_vector_type(2)));

// ---- transpose: full-row blocks (R19 form — ~20us, near BW floor). Regular stores
//      (NT on producer->consumer intermediate costs the consumer +16us — R15 lesson). ----
__global__ __launch_bounds__(256) void transpose_kernel(
    const float* __restrict__ feat, ushort* __restrict__ T)
{
    __shared__ float tile[W][36];   // [x][ch], pad 36: c4*4 reads stay 16B-aligned
    int B = blockIdx.x;
    int y = B % H;
    int s = B / H;                  // slice = cg*NB + nb
    int nb = s & 1, cg = s >> 1;

    int t = threadIdx.x;
    {
        int cl  = t >> 3;
        int xi4 = t & 7;
        const float* src = feat + (((size_t)nb * C + cg * CG + cl) * H + y) * W;
        for (int s4 = xi4; s4 < W / 4; s4 += 8) {
            float4 v = *reinterpret_cast<const float4*>(src + 4 * s4);
            int x = 4 * s4;
            tile[x + 0][cl] = v.x; tile[x + 1][cl] = v.y;
            tile[x + 2][cl] = v.z; tile[x + 3][cl] = v.w;
        }
    }
    __syncthreads();
    {
        int c4 = (t & 7) * 4;
        ushort* dstrow = T + (((size_t)s * H + y) * W) * CG;
        for (int px = t >> 3; px < W; px += 32) {
            float4 v = *reinterpret_cast<const float4*>(&tile[px][c4]);
            uint2 o;
            o.x = __builtin_bit_cast(uint, __builtin_amdgcn_cvt_pkrtz(v.x, v.y));
            o.y = __builtin_bit_cast(uint, __builtin_amdgcn_cvt_pkrtz(v.z, v.w));
            *reinterpret_cast<uint2*>(dstrow + px * CG + c4) = o;
        }
    }
}

// per-roi corner tables: 16 offsets + packed-h2 weights, all in registers
__device__ __forceinline__ void corner_tables(
    const float* __restrict__ r, int ph, int pw, int* offv, uint* wgtv)
{
    float x1 = r[1]*SCALE, y1 = r[2]*SCALE, x2 = r[3]*SCALE, y2 = r[4]*SCALE;
    float bw = fmaxf(x2 - x1, 1.0f) * (1.0f / PW);
    float bh = fmaxf(y2 - y1, 1.0f) * (1.0f / PH);

    int yr[2][2]; float wy[2][2];
    int xr[2][2]; float wx[2][2];
    #pragma unroll
    for (int s = 0; s < 2; ++s) {
        float y = y1 + (float)ph * bh + ((float)s + 0.5f) * bh * 0.5f;
        bool v = (y >= -1.0f) && (y <= (float)H);
        float yc = fmaxf(y, 0.0f);
        int lo = (int)yc, hi;
        if (lo >= H - 1) { lo = H - 1; hi = H - 1; yc = (float)(H - 1); }
        else             { hi = lo + 1; }
        float l = yc - (float)lo;
        yr[s][0] = lo; yr[s][1] = hi;
        wy[s][0] = v ? 1.0f - l : 0.0f;
        wy[s][1] = v ? l        : 0.0f;
    }
    #pragma unroll
    for (int s = 0; s < 2; ++s) {
        float x = x1 + (float)pw * bw + ((float)s + 0.5f) * bw * 0.5f;
        bool v = (x >= -1.0f) && (x <= (float)W);
        float xc = fmaxf(x, 0.0f);
        int lo = (int)xc, hi;
        if (lo >= W - 1) { lo = W - 1; hi = W - 1; xc = (float)(W - 1); }
        else             { hi = lo + 1; }
        float l = xc - (float)lo;
        xr[s][0] = lo; xr[s][1] = hi;
        wx[s][0] = v ? 1.0f - l : 0.0f;
        wx[s][1] = v ? l        : 0.0f;
    }
    #pragma unroll
    for (int cr = 0; cr < 16; ++cr) {
        int sy = (cr >> 3) & 1, sx = (cr >> 2) & 1, cy = (cr >> 1) & 1, cx = cr & 1;
        offv[cr] = (yr[sy][cy] * W + xr[sx][cx]) * CG;
        float w = wy[sy][cy] * wx[sx][cx] * 0.25f;
        wgtv[cr] = __builtin_bit_cast(uint, __builtin_amdgcn_cvt_pkrtz(w, w));
    }
}

#define H2C(u) (__builtin_bit_cast(h2, (uint)(u)))

// ---- gather: 2 rois per block, software-pipelined so roi1's loads are in flight while
//      roi0's epilogue stores run. All-register tables + MLP-16 + packed f16 FMA. ----
__global__ __launch_bounds__(256) void gather_kernel(
    const ushort* __restrict__ T, const float* __restrict__ rois,
    float* __restrict__ out, int K, int PK)
{
    __shared__ float s_out[CG * 49];

    int B  = blockIdx.x;
    int cg = B & 7;                 // cgroup pinned to XCD (consecutive blocks round-robin XCDs)
    int j  = B >> 3;
    int p  = j / PK, jj = j - p * PK;  // phase p = batch slice; per-XCD L2 slice resident
    int k0 = 2 * jj, k1 = k0 + 1;

    const float* r0 = rois + (size_t)k0 * 5;
    bool have1 = (k1 < K);
    const float* r1 = rois + (size_t)(have1 ? k1 : k0) * 5;
    bool do0 = ((int)r0[0] == p);
    bool do1 = have1 && ((int)r1[0] == p);
    if (!do0 && !do1) return;       // block-uniform exit before any barrier

    int t = threadIdx.x;
    int bin = t >> 2, q = t & 3;
    int ph = bin / 7, pw = bin - ph * 7;
    bool lane_ok = (t < 49 * 4);
    const ushort* slab = T + ((size_t)(cg * NB + p) * H * W) * CG + q * 8;

    // ---- roi0: gather + stage ----
    if (lane_ok && do0) {
        int  offv[16]; uint wgtv[16];
        corner_tables(r0, ph, pw, offv, wgtv);
        uint4 d[16];
        #pragma unroll
        for (int cr = 0; cr < 16; ++cr)
            d[cr] = *reinterpret_cast<const uint4*>(slab + offv[cr]);
        h2 a01 = {0,0}, a23 = {0,0}, a45 = {0,0}, a67 = {0,0};
        #pragma unroll
        for (int cr = 0; cr < 16; ++cr) {
            h2 wpk = H2C(wgtv[cr]);
            a01 += H2C(d[cr].x) * wpk;  a23 += H2C(d[cr].y) * wpk;
            a45 += H2C(d[cr].z) * wpk;  a67 += H2C(d[cr].w) * wpk;
        }
        float* so = s_out + (8 * q) * 49 + bin;
        so[0*49] = (float)a01.x; so[1*49] = (float)a01.y;
        so[2*49] = (float)a23.x; so[3*49] = (float)a23.y;
        so[4*49] = (float)a45.x; so[5*49] = (float)a45.y;
        so[6*49] = (float)a67.x; so[7*49] = (float)a67.y;
    }
    __syncthreads();

    // ---- roi1: ISSUE loads now (they stay in flight under roi0's epilogue stores) ----
    uint4 e[16];
    uint  wgt1[16];
    if (lane_ok && do1) {
        int offv1[16];
        corner_tables(r1, ph, pw, offv1, wgt1);
        #pragma unroll
        for (int cr = 0; cr < 16; ++cr)
            e[cr] = *reinterpret_cast<const uint4*>(slab + offv1[cr]);
    }

    // ---- roi0 epilogue: coalesced NT write (overlaps roi1 load latency) ----
    if (do0) {
        float* oslab = out + ((size_t)k0 * C + cg * CG) * (PH * PW);
        for (int i4 = t; i4 < (CG * 49) / 4; i4 += 256) {
            f32x4 v = *reinterpret_cast<const f32x4*>(s_out + 4 * i4);
            __builtin_nontemporal_store(v, reinterpret_cast<f32x4*>(oslab + 4 * i4));
        }
    }
    if (!do1) return;

    // ---- roi1: consume + stage ----
    __syncthreads();                // write0 readers done; s_out reusable
    if (lane_ok) {
        h2 a01 = {0,0}, a23 = {0,0}, a45 = {0,0}, a67 = {0,0};
        #pragma unroll
        for (int cr = 0; cr < 16; ++cr) {
            h2 wpk = H2C(wgt1[cr]);
            a01 += H2C(e[cr].x) * wpk;  a23 += H2C(e[cr].y) * wpk;
            a45 += H2C(e[cr].z) * wpk;  a67 += H2C(e[cr].w) * wpk;
        }
        float* so = s_out + (8 * q) * 49 + bin;
        so[0*49] = (float)a01.x; so[1*49] = (float)a01.y;
        so[2*49] = (float)a23.x; so[3*49] = (float)a23.y;
        so[4*49] = (float)a45.x; so[5*49] = (float)a45.y;
        so[6*49] = (float)a67.x; so[7*49] = (float)a67.y;
    }
    __syncthreads();

    {
        float* oslab = out + ((size_t)k1 * C + cg * CG) * (PH * PW);
        for (int i4 = t; i4 < (CG * 49) / 4; i4 += 256) {
            f32x4 v = *reinterpret_cast<const f32x4*>(s_out + 4 * i4);
            __builtin_nontemporal_store(v, reinterpret_cast<f32x4*>(oslab + 4 * i4));
        }
    }
}
#undef H2C

// ---------------- fallback (R4 kernel) if workspace too small ----------------
struct __attribute__((packed, aligned(4))) f2 { float a, b; };

__global__ __launch_bounds__(256) void roi_align_fallback(
    const float* __restrict__ feat, const float* __restrict__ rois,
    float* __restrict__ out, int K)
{
    __shared__ int   s_ylo[NS], s_yhi[NS];
    __shared__ float s_wy[NS][2];
    __shared__ int   s_xb[NS];
    __shared__ float s_wx[NS][2];

    int B   = blockIdx.x;
    int xcd = B & 7;
    int j   = B >> 3;
    int p   = j / K, k = j - p * K;
    int cb  = (p * 8 + xcd) * CGF;

    const float* r = rois + (size_t)k * 5;
    int   b  = (int)r[0];
    float x1 = r[1]*SCALE, y1 = r[2]*SCALE, x2 = r[3]*SCALE, y2 = r[4]*SCALE;
    float bw = fmaxf(x2 - x1, 1.0f) * (1.0f / PW);
    float bh = fmaxf(y2 - y1, 1.0f) * (1.0f / PH);

    int t = threadIdx.x;
    if (t < NS) {
        int ph = t >> 1, s = t & 1;
        float y = y1 + (float)ph * bh + ((float)s + 0.5f) * bh * 0.5f;
        bool v = (y >= -1.0f) && (y <= (float)H);
        float yc = fmaxf(y, 0.0f);
        int lo = (int)yc, hi;
        if (lo >= H - 1) { lo = H - 1; hi = H - 1; yc = (float)(H - 1); }
        else             { hi = lo + 1; }
        float l = yc - (float)lo;
        s_ylo[t] = lo; s_yhi[t] = hi;
        s_wy[t][0] = v ? 1.0f - l : 0.0f;
        s_wy[t][1] = v ? l        : 0.0f;
    } else if (t >= 64 && t < 64 + NS) {
        int i = t - 64, pw = i >> 1, s = i & 1;
        float x = x1 + (float)pw * bw + ((float)s + 0.5f) * bw * 0.5f;
        bool v = (x >= -1.0f) && (x <= (float)W);
        float xc = fmaxf(x, 0.0f);
        int lo = (int)xc;
        if (lo >= W - 1) {
            s_xb[i] = W - 2; s_wx[i][0] = 0.0f; s_wx[i][1] = v ? 1.0f : 0.0f;
        } else {
            float l = xc - (float)lo;
            s_xb[i] = lo; s_wx[i][0] = v ? 1.0f - l : 0.0f; s_wx[i][1] = v ? l : 0.0f;
        }
    }
    __syncthreads();

    const float* img = feat + (size_t)b * (C * H * W);
    float* out_base = out + ((size_t)k * C + cb) * (PH * PW);

    for (int i = t; i < CGF * PH * PW; i += 256) {
        int cl  = i / (PH * PW);
        int bin = i - cl * (PH * PW);
        int ph  = bin / PW;
        int pw  = bin - ph * PW;
        const float* plane = img + (size_t)(cb + cl) * (H * W);

        float acc = 0.0f;
        #pragma unroll
        for (int sy = 0; sy < 2; ++sy) {
            int ysi = 2 * ph + sy;
            const float* rlo = plane + s_ylo[ysi] * W;
            const float* rhi = plane + s_yhi[ysi] * W;
            float hy = s_wy[ysi][0], ly = s_wy[ysi][1];
            #pragma unroll
            for (int sx = 0; sx < 2; ++sx) {
                int xsi = 2 * pw + sx;
                int xb = s_xb[xsi];
                float w0 = s_wx[xsi][0], w1 = s_wx[xsi][1];
                f2 vlo = *reinterpret_cast<const f2*>(rlo + xb);
                f2 vhi = *reinterpret_cast<const f2*>(rhi + xb);
                acc += hy * (w0 * vlo.a + w1 * vlo.b)
                     + ly * (w0 * vhi.a + w1 * vhi.b);
            }
        }
        __builtin_nontemporal_store(acc * 0.25f, &out_base[i]);
    }
}

extern "C" void kernel_launch(void* const* d_in, const int* in_sizes, int n_in,
                              void* d_out, int out_size, void* d_ws, size_t ws_size,
                              hipStream_t stream) {
    const float* feat = (const float*)d_in[0];
    const float* rois = (const float*)d_in[1];
    float* out = (float*)d_out;
    int K = in_sizes[1] / 5;

    size_t need = (size_t)NCG * NB * H * W * CG * sizeof(ushort);  // ~41 MB
    if (ws_size >= need) {
        ushort* T = (ushort*)d_ws;
        int tblocks = NCG * NB * H;   // 3200 full-row blocks
        transpose_kernel<<<tblocks, 256, 0, stream>>>(feat, T);
        int PK = (K + 1) / 2;         // roi pairs per phase
        gather_kernel<<<PK * NB * 8, 256, 0, stream>>>(T, rois, out, K, PK);
    } else {
        roi_align_fallback<<<K * NGROUPF, 256, 0, stream>>>(feat, rois, out, K);
    }
}

// Round 22
// 51.540 us; speedup vs baseline: 1.0562x; 1.0562x over previous
//
#include <hip/hip_runtime.h>

// RoIAlign (torchvision semantics, aligned=false, sampling_ratio=2)
// features: [N=2, C=256, H=200, W=200] f32, rois: [K,5], out: [K,256,7,7] f32
constexpr int C = 256, H = 200, W = 200, NB = 2;
constexpr int PH = 7, PW = 7;
constexpr int NS = 14;             // fallback only
constexpr float SCALE = 0.125f;
// transposed tensor: T[cg:8][nb:2][y][x][32ch] f16 — 64B per (pixel,cgroup) = 1 line
constexpr int CG = 32, NCG = C / CG;
// fallback (R4) tiling
constexpr int CGF = 8, NGROUPF = C / CGF;

typedef float    f32x4 __attribute__((ext_vector_type(4)));
typedef _Float16 h2    __attribute__((ext_vector_type(2)));

// ---- transpose: full-row blocks (~20us, near the 19.5us BW floor). Regular stores
//      (NT on producer->consumer intermediate costs the consumer +16us — R15 lesson). ----
__global__ __launch_bounds__(256) void transpose_kernel(
    const float* __restrict__ feat, ushort* __restrict__ T)
{
    __shared__ float tile[W][36];   // [x][ch], pad 36: c4*4 reads stay 16B-aligned (144B rows)
    int B = blockIdx.x;
    int y = B % H;
    int s = B / H;                  // slice = cg*NB + nb
    int nb = s & 1, cg = s >> 1;

    int t = threadIdx.x;
    {
        int cl  = t >> 3;           // channel 0..31
        int xi4 = t & 7;            // float4-slot start
        const float* src = feat + (((size_t)nb * C + cg * CG + cl) * H + y) * W;
        for (int s4 = xi4; s4 < W / 4; s4 += 8) {       // 50 slots: 6-7 iters/thread
            float4 v = *reinterpret_cast<const float4*>(src + 4 * s4);
            int x = 4 * s4;
            tile[x + 0][cl] = v.x; tile[x + 1][cl] = v.y;
            tile[x + 2][cl] = v.z; tile[x + 3][cl] = v.w;
        }
    }
    __syncthreads();
    {
        int c4 = (t & 7) * 4;       // channel quad
        ushort* dstrow = T + (((size_t)s * H + y) * W) * CG;
        for (int px = t >> 3; px < W; px += 32) {       // contiguous 2KB per 32-px sweep
            float4 v = *reinterpret_cast<const float4*>(&tile[px][c4]);
            uint2 o;
            o.x = __builtin_bit_cast(uint, __builtin_amdgcn_cvt_pkrtz(v.x, v.y));
            o.y = __builtin_bit_cast(uint, __builtin_amdgcn_cvt_pkrtz(v.z, v.w));
            *reinterpret_cast<uint2*>(dstrow + px * CG + c4) = o;
        }
    }
}

// ---- gather: ALL-REGISTER corner table + MLP-16 + packed f16 FMA (R19/R18 best form) ----
__global__ __launch_bounds__(256) void gather_kernel(
    const ushort* __restrict__ T, const float* __restrict__ rois,
    float* __restrict__ out, int K)
{
    __shared__ float s_out[CG * 49];   // [ch][bin] f32 — only LDS use

    int B  = blockIdx.x;
    int cg = B & 7;                 // cgroup pinned to XCD (consecutive blocks round-robin XCDs)
    int j  = B >> 3;
    int p  = j / K, k = j - p * K;  // phase p = batch slice; per-XCD L2 slice = 2.56MB resident

    const float* r = rois + (size_t)k * 5;
    int b = (int)r[0];
    if (b != p) return;             // block-uniform exit before the barrier (phantoms cheap, R17)

    int t = threadIdx.x;
    if (t < 49 * 4) {               // 4 lanes per bin, each owns 8 channels (16B of the 64B line)
        int bin = t >> 2, q = t & 3;
        int ph = bin / 7, pw = bin - ph * 7;

        float x1 = r[1]*SCALE, y1 = r[2]*SCALE, x2 = r[3]*SCALE, y2 = r[4]*SCALE;
        float bw = fmaxf(x2 - x1, 1.0f) * (1.0f / PW);
        float bh = fmaxf(y2 - y1, 1.0f) * (1.0f / PH);

        // axis terms in registers: 2 samples per axis
        int   yr[2][2]; float wy[2][2];
        int   xr[2][2]; float wx[2][2];
        #pragma unroll
        for (int s = 0; s < 2; ++s) {
            float y = y1 + (float)ph * bh + ((float)s + 0.5f) * bh * 0.5f;
            bool v = (y >= -1.0f) && (y <= (float)H);
            float yc = fmaxf(y, 0.0f);
            int lo = (int)yc, hi;
            if (lo >= H - 1) { lo = H - 1; hi = H - 1; yc = (float)(H - 1); }
            else             { hi = lo + 1; }
            float l = yc - (float)lo;
            yr[s][0] = lo; yr[s][1] = hi;
            wy[s][0] = v ? 1.0f - l : 0.0f;
            wy[s][1] = v ? l        : 0.0f;
        }
        #pragma unroll
        for (int s = 0; s < 2; ++s) {
            float x = x1 + (float)pw * bw + ((float)s + 0.5f) * bw * 0.5f;
            bool v = (x >= -1.0f) && (x <= (float)W);
            float xc = fmaxf(x, 0.0f);
            int lo = (int)xc, hi;
            if (lo >= W - 1) { lo = W - 1; hi = W - 1; xc = (float)(W - 1); }
            else             { hi = lo + 1; }
            float l = xc - (float)lo;
            xr[s][0] = lo; xr[s][1] = hi;
            wx[s][0] = v ? 1.0f - l : 0.0f;
            wx[s][1] = v ? l        : 0.0f;
        }

        // 16 corner offsets + packed weights, fully unrolled (static indices -> registers)
        int  offv[16];
        uint wgtv[16];
        #pragma unroll
        for (int cr = 0; cr < 16; ++cr) {
            int sy = (cr >> 3) & 1, sx = (cr >> 2) & 1, cy = (cr >> 1) & 1, cx = cr & 1;
            offv[cr] = (yr[sy][cy] * W + xr[sx][cx]) * CG;
            float w = wy[sy][cy] * wx[sx][cx] * 0.25f;
            wgtv[cr] = __builtin_bit_cast(uint, __builtin_amdgcn_cvt_pkrtz(w, w));
        }

        const ushort* slab = T + ((size_t)(cg * NB + p) * H * W) * CG + q * 8;
        // issue ALL 16 corner loads (MLP=16) — no barriers, no LDS on the path
        uint4 d[16];
        #pragma unroll
        for (int cr = 0; cr < 16; ++cr)
            d[cr] = *reinterpret_cast<const uint4*>(slab + offv[cr]);

        h2 a01 = {0, 0}, a23 = {0, 0}, a45 = {0, 0}, a67 = {0, 0};
        #define H2(u) (__builtin_bit_cast(h2, (uint)(u)))
        #pragma unroll
        for (int cr = 0; cr < 16; ++cr) {
            h2 wpk = H2(wgtv[cr]);
            a01 += H2(d[cr].x) * wpk;  a23 += H2(d[cr].y) * wpk;
            a45 += H2(d[cr].z) * wpk;  a67 += H2(d[cr].w) * wpk;
        }
        #undef H2

        float* so = s_out + (8 * q) * 49 + bin;
        so[0*49] = (float)a01.x; so[1*49] = (float)a01.y;
        so[2*49] = (float)a23.x; so[3*49] = (float)a23.y;
        so[4*49] = (float)a45.x; so[5*49] = (float)a45.y;
        so[6*49] = (float)a67.x; so[7*49] = (float)a67.y;
    }
    __syncthreads();

    // coalesced contiguous write: out[k][cg*32 .. cg*32+31][0..48] (terminal output -> NT ok)
    float* oslab = out + ((size_t)k * C + cg * CG) * (PH * PW);
    for (int i4 = t; i4 < (CG * 49) / 4; i4 += 256) {
        f32x4 v = *reinterpret_cast<const f32x4*>(s_out + 4 * i4);
        __builtin_nontemporal_store(v, reinterpret_cast<f32x4*>(oslab + 4 * i4));
    }
}

// ---------------- fallback (R4 kernel) if workspace too small ----------------
struct __attribute__((packed, aligned(4))) f2 { float a, b; };

__global__ __launch_bounds__(256) void roi_align_fallback(
    const float* __restrict__ feat, const float* __restrict__ rois,
    float* __restrict__ out, int K)
{
    __shared__ int   s_ylo[NS], s_yhi[NS];
    __shared__ float s_wy[NS][2];
    __shared__ int   s_xb[NS];
    __shared__ float s_wx[NS][2];

    int B   = blockIdx.x;
    int xcd = B & 7;
    int j   = B >> 3;
    int p   = j / K, k = j - p * K;
    int cb  = (p * 8 + xcd) * CGF;

    const float* r = rois + (size_t)k * 5;
    int   b  = (int)r[0];
    float x1 = r[1]*SCALE, y1 = r[2]*SCALE, x2 = r[3]*SCALE, y2 = r[4]*SCALE;
    float bw = fmaxf(x2 - x1, 1.0f) * (1.0f / PW);
    float bh = fmaxf(y2 - y1, 1.0f) * (1.0f / PH);

    int t = threadIdx.x;
    if (t < NS) {
        int ph = t >> 1, s = t & 1;
        float y = y1 + (float)ph * bh + ((float)s + 0.5f) * bh * 0.5f;
        bool v = (y >= -1.0f) && (y <= (float)H);
        float yc = fmaxf(y, 0.0f);
        int lo = (int)yc, hi;
        if (lo >= H - 1) { lo = H - 1; hi = H - 1; yc = (float)(H - 1); }
        else             { hi = lo + 1; }
        float l = yc - (float)lo;
        s_ylo[t] = lo; s_yhi[t] = hi;
        s_wy[t][0] = v ? 1.0f - l : 0.0f;
        s_wy[t][1] = v ? l        : 0.0f;
    } else if (t >= 64 && t < 64 + NS) {
        int i = t - 64, pw = i >> 1, s = i & 1;
        float x = x1 + (float)pw * bw + ((float)s + 0.5f) * bw * 0.5f;
        bool v = (x >= -1.0f) && (x <= (float)W);
        float xc = fmaxf(x, 0.0f);
        int lo = (int)xc;
        if (lo >= W - 1) {
            s_xb[i] = W - 2; s_wx[i][0] = 0.0f; s_wx[i][1] = v ? 1.0f : 0.0f;
        } else {
            float l = xc - (float)lo;
            s_xb[i] = lo; s_wx[i][0] = v ? 1.0f - l : 0.0f; s_wx[i][1] = v ? l : 0.0f;
        }
    }
    __syncthreads();

    const float* img = feat + (size_t)b * (C * H * W);
    float* out_base = out + ((size_t)k * C + cb) * (PH * PW);

    for (int i = t; i < CGF * PH * PW; i += 256) {
        int cl  = i / (PH * PW);
        int bin = i - cl * (PH * PW);
        int ph  = bin / PW;
        int pw  = bin - ph * PW;
        const float* plane = img + (size_t)(cb + cl) * (H * W);

        float acc = 0.0f;
        #pragma unroll
        for (int sy = 0; sy < 2; ++sy) {
            int ysi = 2 * ph + sy;
            const float* rlo = plane + s_ylo[ysi] * W;
            const float* rhi = plane + s_yhi[ysi] * W;
            float hy = s_wy[ysi][0], ly = s_wy[ysi][1];
            #pragma unroll
            for (int sx = 0; sx < 2; ++sx) {
                int xsi = 2 * pw + sx;
                int xb = s_xb[xsi];
                float w0 = s_wx[xsi][0], w1 = s_wx[xsi][1];
                f2 vlo = *reinterpret_cast<const f2*>(rlo + xb);
                f2 vhi = *reinterpret_cast<const f2*>(rhi + xb);
                acc += hy * (w0 * vlo.a + w1 * vlo.b)
                     + ly * (w0 * vhi.a + w1 * vhi.b);
            }
        }
        __builtin_nontemporal_store(acc * 0.25f, &out_base[i]);
    }
}

extern "C" void kernel_launch(void* const* d_in, const int* in_sizes, int n_in,
                              void* d_out, int out_size, void* d_ws, size_t ws_size,
                              hipStream_t stream) {
    const float* feat = (const float*)d_in[0];
    const float* rois = (const float*)d_in[1];
    float* out = (float*)d_out;
    int K = in_sizes[1] / 5;

    size_t need = (size_t)NCG * NB * H * W * CG * sizeof(ushort);  // ~41 MB
    if (ws_size >= need) {
        ushort* T = (ushort*)d_ws;
        int tblocks = NCG * NB * H;   // 3200 full-row blocks
        transpose_kernel<<<tblocks, 256, 0, stream>>>(feat, T);
        gather_kernel<<<K * NCG * NB, 256, 0, stream>>>(T, rois, out, K);
    } else {
        roi_align_fallback<<<K * NGROUPF, 256, 0, stream>>>(feat, rois, out, K);
    }
}